// Round 5
// baseline (284.655 us; speedup 1.0000x reference)
//
#include <hip/hip_runtime.h>
#include <math.h>

#define N 512
#define H 128
#define L 4
#define NUM_RBF 50
#define NMOL 16
#define QSPL 4            // i-range splits per j in k_msg
#define FK 64             // padded K (53 features + 11 zeros)

typedef __attribute__((ext_vector_type(8))) short short8;
typedef __attribute__((ext_vector_type(4))) float float4v;

__device__ __forceinline__ float silu_f(float v) {
    return v / (1.0f + __expf(-v));
}

__device__ __forceinline__ unsigned short f2bf(float f) {
    unsigned int u = __float_as_uint(f);
    unsigned int r = (u + 0x7FFFu + ((u >> 16) & 1u)) >> 16;  // RNE
    return (unsigned short)r;
}

// One-shot geometry kernel: F[(j*N+i)*64 + k] = bf16 feature k of pair (i,j)
// (50 RBF + 3 dir + 11 zero pad), validf[j*N+i] = (d<5 && i!=j).
// Block = (j, i-quarter); thread: il = tid>>1 (i within quarter), kh = tid&1.
__global__ __launch_bounds__(256) void k_feat(const float* __restrict__ pos,
                                              unsigned short* __restrict__ Fg,
                                              float* __restrict__ validf) {
    int bx = blockIdx.x;
    int j = bx >> 2;
    int q = bx & 3;
    int tid = threadIdx.x;
    int il = tid >> 1;
    int kh = tid & 1;
    int i = q * 128 + il;

    float dx = pos[i * 3 + 0] - pos[j * 3 + 0];
    float dy = pos[i * 3 + 1] - pos[j * 3 + 1];
    float dz = pos[i * 3 + 2] - pos[j * 3 + 2];
    float d = sqrtf(dx * dx + dy * dy + dz * dz);
    float rinv = 1.0f / fmaxf(d, 1e-8f);
    const float DELTA = 5.0f / 49.0f;

    unsigned short vals[32];
#pragma unroll
    for (int t = 0; t < 32; t++) {
        int k = kh * 32 + t;
        float v;
        if (k < NUM_RBF) {
            float tt = d - (float)k * DELTA;
            v = __expf(-50.0f * tt * tt);          // 1/(2*0.1^2) = 50
        } else if (k == NUM_RBF)     v = dx * rinv;
        else if (k == NUM_RBF + 1)   v = dy * rinv;
        else if (k == NUM_RBF + 2)   v = dz * rinv;
        else                         v = 0.0f;
        vals[t] = f2bf(v);
    }
    short8* dst = (short8*)&Fg[((size_t)(j * N + i)) * FK + kh * 32];
#pragma unroll
    for (int p = 0; p < 4; p++) {
        short8 o;
#pragma unroll
        for (int e = 0; e < 8; e++) o[e] = (short)vals[p * 8 + e];
        dst[p] = o;
    }
    if (kh == 0) validf[j * N + i] = (float)((d < 5.0f) && (i != j));
}

// x[i,h] = embed[clip(an[i])]; a[i,h] = b1[h] + x[i,:] @ Wx[:,h]
__global__ __launch_bounds__(H) void k_embed_lin(const int* __restrict__ an,
                                                 const float* __restrict__ embed,
                                                 const float* __restrict__ wx,
                                                 const float* __restrict__ b1,
                                                 float* __restrict__ x,
                                                 float* __restrict__ a) {
    int i = blockIdx.x, h = threadIdx.x;
    __shared__ float xs[H];
    int z = an[i];
    z = min(max(z, 0), 99);
    float xv = embed[z * H + h];
    x[i * H + h] = xv;
    xs[h] = xv;
    __syncthreads();
    float a0 = b1[h], a1 = 0.f, a2 = 0.f, a3 = 0.f;
#pragma unroll 8
    for (int k = 0; k < H; k += 4) {
        a0 += xs[k]     * wx[(k)     * H + h];
        a1 += xs[k + 1] * wx[(k + 1) * H + h];
        a2 += xs[k + 2] * wx[(k + 2) * H + h];
        a3 += xs[k + 3] * wx[(k + 3) * H + h];
    }
    a[i * H + h] = (a0 + a1) + (a2 + a3);
}

// Barrier-free MFMA message kernel. Block = (j, i-quarter). Grid = QSPL*N.
// 256 threads = 4 waves; wave wv owns h-slice [32wv, 32wv+32).
// msum4[q,j,h] = sum_{i in quarter} valid(i,j) * silu( a[i,h] + F_ij @ wfeat[:,h] )
__global__ __launch_bounds__(256) void k_msg(const float* __restrict__ a,
                                             const unsigned short* __restrict__ Fg,
                                             const float* __restrict__ validf,
                                             const float* __restrict__ wfeat,
                                             float* __restrict__ msum4,
                                             int* __restrict__ cnt4) {
    int bx = blockIdx.x;
    int j = bx >> 2;
    int q = bx & (QSPL - 1);
    int tid = threadIdx.x;
    int lane = tid & 63;
    int wv = tid >> 6;        // wave 0..3
    int nn = lane & 15;       // tile column
    int quad = lane >> 4;     // 0..3
    int hbase = wv * 32;

    // B fragments: B[k = 32c + quad*8+jj][n = hbase + 16t + nn]
    short8 bfrag[2][2];
    for (int c = 0; c < 2; c++) {
        for (int t = 0; t < 2; t++) {
            short8 b;
            int h = hbase + 16 * t + nn;
#pragma unroll
            for (int jj = 0; jj < 8; jj++) {
                int k = c * 32 + quad * 8 + jj;
                float v = (k < NUM_RBF + 3) ? wfeat[k * H + h] : 0.0f;
                b[jj] = (short)f2bf(v);
            }
            bfrag[c][t] = b;
        }
    }

    const unsigned short* Frow = Fg + (size_t)j * N * FK;
    float pacc0 = 0.0f, pacc1 = 0.0f, pcnt = 0.0f;

#pragma unroll 2
    for (int it = 0; it < 8; it++) {
        int ib = q * 128 + it * 16;
        int irow = ib + nn;
        // A frags straight from global: row = i, k-bytes contiguous per lane.
        short8 af0 = *(const short8*)(Frow + (size_t)irow * FK + quad * 8);
        short8 af1 = *(const short8*)(Frow + (size_t)irow * FK + 32 + quad * 8);
        int ibq = ib + quad * 4;
        float4v vm4 = *(const float4v*)&validf[j * N + ibq];
        float av0[4], av1[4];
#pragma unroll
        for (int r = 0; r < 4; r++) {
            av0[r] = a[(ibq + r) * H + hbase + nn];
            av1[r] = a[(ibq + r) * H + hbase + 16 + nn];
        }
        float4v acc0 = {0.0f, 0.0f, 0.0f, 0.0f};
        float4v acc1 = {0.0f, 0.0f, 0.0f, 0.0f};
        acc0 = __builtin_amdgcn_mfma_f32_16x16x32_bf16(af0, bfrag[0][0], acc0, 0, 0, 0);
        acc0 = __builtin_amdgcn_mfma_f32_16x16x32_bf16(af1, bfrag[1][0], acc0, 0, 0, 0);
        acc1 = __builtin_amdgcn_mfma_f32_16x16x32_bf16(af0, bfrag[0][1], acc1, 0, 0, 0);
        acc1 = __builtin_amdgcn_mfma_f32_16x16x32_bf16(af1, bfrag[1][1], acc1, 0, 0, 0);
#pragma unroll
        for (int r = 0; r < 4; r++) {
            pacc0 += vm4[r] * silu_f(acc0[r] + av0[r]);
            pacc1 += vm4[r] * silu_f(acc1[r] + av1[r]);
        }
        pcnt += (vm4[0] + vm4[1]) + (vm4[2] + vm4[3]);
    }

    // reduce over quads (lanes nn, nn+16, nn+32, nn+48 share a column)
    pacc0 += __shfl_xor(pacc0, 16, 64);
    pacc0 += __shfl_xor(pacc0, 32, 64);
    pacc1 += __shfl_xor(pacc1, 16, 64);
    pacc1 += __shfl_xor(pacc1, 32, 64);
    pcnt  += __shfl_xor(pcnt, 16, 64);
    pcnt  += __shfl_xor(pcnt, 32, 64);
    if (lane < 16) {
        msum4[(q * N + j) * H + hbase + nn]      = pacc0;
        msum4[(q * N + j) * H + hbase + 16 + nn] = pacc1;
    }
    if (tid == 0) cnt4[q * N + j] = (int)(pcnt + 0.5f);
}

// 4-way split-K update: 512 threads = 4 groups of 128.
__global__ __launch_bounds__(512) void k_update(const float* __restrict__ msum4,
                                                const int* __restrict__ cnt4,
                                                const float* __restrict__ w2,
                                                const float* __restrict__ b2,
                                                const float* __restrict__ u1,
                                                const float* __restrict__ ub1,
                                                const float* __restrict__ u2,
                                                const float* __restrict__ ub2,
                                                float* __restrict__ x,
                                                const float* __restrict__ wxn,
                                                const float* __restrict__ b1n,
                                                float* __restrict__ a_next) {
    int j = blockIdx.x;
    int h = threadIdx.x & 127;
    int grp = threadIdx.x >> 7;   // 0..3

    __shared__ float sj[H], xj[H], ag[H], hid[H], xn[H];
    __shared__ float part[4][H];

    if (grp == 0) {
        xj[h] = x[j * H + h];
    } else if (grp == 1) {
        sj[h] = msum4[j * H + h] + msum4[(N + j) * H + h]
              + msum4[(2 * N + j) * H + h] + msum4[(3 * N + j) * H + h];
    }
    int c = cnt4[j] + cnt4[N + j] + cnt4[2 * N + j] + cnt4[3 * N + j];
    __syncthreads();

    {
        float p0 = 0.f, p1 = 0.f, p2 = 0.f, p3 = 0.f;
        int k0 = grp * 32;
#pragma unroll 8
        for (int k = 0; k < 32; k += 4) {
            p0 += sj[k0 + k]     * w2[(k0 + k)     * H + h];
            p1 += sj[k0 + k + 1] * w2[(k0 + k + 1) * H + h];
            p2 += sj[k0 + k + 2] * w2[(k0 + k + 2) * H + h];
            p3 += sj[k0 + k + 3] * w2[(k0 + k + 3) * H + h];
        }
        part[grp][h] = (p0 + p1) + (p2 + p3);
    }
    __syncthreads();
    if (grp == 0) ag[h] = part[0][h] + part[1][h] + part[2][h] + part[3][h] + (float)c * b2[h];
    __syncthreads();

    {
        const float* src = (grp < 2) ? xj : ag;
        int sbase = (grp & 1) * 64;
        int k0 = grp * 64;
        float p0 = 0.f, p1 = 0.f, p2 = 0.f, p3 = 0.f;
#pragma unroll 8
        for (int k = 0; k < 64; k += 4) {
            p0 += src[sbase + k]     * u1[(k0 + k)     * H + h];
            p1 += src[sbase + k + 1] * u1[(k0 + k + 1) * H + h];
            p2 += src[sbase + k + 2] * u1[(k0 + k + 2) * H + h];
            p3 += src[sbase + k + 3] * u1[(k0 + k + 3) * H + h];
        }
        part[grp][h] = (p0 + p1) + (p2 + p3);
    }
    __syncthreads();
    if (grp == 0) hid[h] = silu_f(part[0][h] + part[1][h] + part[2][h] + part[3][h] + ub1[h]);
    __syncthreads();

    {
        float p0 = 0.f, p1 = 0.f, p2 = 0.f, p3 = 0.f;
        int k0 = grp * 32;
#pragma unroll 8
        for (int k = 0; k < 32; k += 4) {
            p0 += hid[k0 + k]     * u2[(k0 + k)     * H + h];
            p1 += hid[k0 + k + 1] * u2[(k0 + k + 1) * H + h];
            p2 += hid[k0 + k + 2] * u2[(k0 + k + 2) * H + h];
            p3 += hid[k0 + k + 3] * u2[(k0 + k + 3) * H + h];
        }
        part[grp][h] = (p0 + p1) + (p2 + p3);
    }
    __syncthreads();
    if (grp == 0) {
        float xv = xj[h] + part[0][h] + part[1][h] + part[2][h] + part[3][h] + ub2[h];
        x[j * H + h] = xv;
        xn[h] = xv;
    }

    if (a_next != nullptr) {
        __syncthreads();
        float p0 = 0.f, p1 = 0.f, p2 = 0.f, p3 = 0.f;
        int k0 = grp * 32;
#pragma unroll 8
        for (int k = 0; k < 32; k += 4) {
            p0 += xn[k0 + k]     * wxn[(k0 + k)     * H + h];
            p1 += xn[k0 + k + 1] * wxn[(k0 + k + 1) * H + h];
            p2 += xn[k0 + k + 2] * wxn[(k0 + k + 2) * H + h];
            p3 += xn[k0 + k + 3] * wxn[(k0 + k + 3) * H + h];
        }
        part[grp][h] = (p0 + p1) + (p2 + p3);
        __syncthreads();
        if (grp == 0)
            a_next[j * H + h] = part[0][h] + part[1][h] + part[2][h] + part[3][h] + b1n[h];
    }
}

// per-molecule mean pool + 2-layer output MLP. 256 threads = 2 i-halves.
__global__ __launch_bounds__(256) void k_pool(const float* __restrict__ x,
                                              const int* __restrict__ batch,
                                              const float* __restrict__ ow1,
                                              const float* __restrict__ ob1,
                                              const float* __restrict__ ow2,
                                              const float* __restrict__ ob2,
                                              float* __restrict__ out) {
    int m = blockIdx.x;
    int h = threadIdx.x & 127;
    int half = threadIdx.x >> 7;
    __shared__ float sp[2][H];
    __shared__ int cp[2];
    __shared__ float pooled[H];
    __shared__ float hid[H / 2];

    float s = 0.0f;
    int cntm = 0;
    for (int i = half * (N / 2); i < (half + 1) * (N / 2); i++) {
        if (batch[i] == m) { s += x[i * H + h]; cntm++; }
    }
    sp[half][h] = s;
    if (h == 0) cp[half] = cntm;
    __syncthreads();

    if (half == 0) pooled[h] = (sp[0][h] + sp[1][h]) / (float)max(cp[0] + cp[1], 1);
    __syncthreads();

    if (half == 0 && h < H / 2) {
        float p0 = 0.f, p1 = 0.f;
        for (int k = 0; k < H; k += 2) {
            p0 += pooled[k]     * ow1[(k)     * (H / 2) + h];
            p1 += pooled[k + 1] * ow1[(k + 1) * (H / 2) + h];
        }
        hid[h] = silu_f(p0 + p1 + ob1[h]);
    }
    __syncthreads();

    if (threadIdx.x == 0) {
        float o = ob2[0];
        for (int k = 0; k < H / 2; k++) o += hid[k] * ow2[k];
        out[m] = o;
    }
}

extern "C" void kernel_launch(void* const* d_in, const int* in_sizes, int n_in,
                              void* d_out, int out_size, void* d_ws, size_t ws_size,
                              hipStream_t stream) {
    const int*   an      = (const int*)d_in[0];
    const float* pos     = (const float*)d_in[1];
    const int*   batch   = (const int*)d_in[2];
    const float* embed   = (const float*)d_in[3];
    const float* msg_w1  = (const float*)d_in[4];   // L x 181 x 128
    const float* msg_b1  = (const float*)d_in[5];
    const float* msg_w2  = (const float*)d_in[6];   // L x 128 x 128
    const float* msg_b2  = (const float*)d_in[7];
    const float* upd_w1  = (const float*)d_in[8];   // L x 256 x 128
    const float* upd_b1  = (const float*)d_in[9];
    const float* upd_w2  = (const float*)d_in[10];  // L x 128 x 128
    const float* upd_b2  = (const float*)d_in[11];
    const float* out_w1  = (const float*)d_in[12];  // 128 x 64
    const float* out_b1  = (const float*)d_in[13];
    const float* out_w2  = (const float*)d_in[14];  // 64 x 1
    const float* out_b2  = (const float*)d_in[15];
    float* out = (float*)d_out;

    unsigned short* Fg = (unsigned short*)d_ws;                 // N*N*FK bf16
    float* validf = (float*)(Fg + (size_t)N * N * FK);          // N*N
    float* x      = validf + (size_t)N * N;                     // N*H
    float* a      = x + N * H;                                  // N*H
    float* msum4  = a + N * H;                                  // QSPL*N*H
    int*   cnt4   = (int*)(msum4 + QSPL * N * H);               // QSPL*N

    const int W1ROWS = H + NUM_RBF + 3;  // 181

    k_feat<<<QSPL * N, 256, 0, stream>>>(pos, Fg, validf);
    k_embed_lin<<<N, H, 0, stream>>>(an, embed, msg_w1, msg_b1, x, a);
    for (int l = 0; l < L; l++) {
        k_msg<<<QSPL * N, 256, 0, stream>>>(a, Fg, validf,
                                            msg_w1 + l * W1ROWS * H + H * H,
                                            msum4, cnt4);
        const float* wxn = (l + 1 < L) ? (msg_w1 + (l + 1) * W1ROWS * H) : nullptr;
        const float* b1n = (l + 1 < L) ? (msg_b1 + (l + 1) * H) : nullptr;
        float* an_ = (l + 1 < L) ? a : nullptr;
        k_update<<<N, 512, 0, stream>>>(msum4, cnt4,
                                        msg_w2 + l * H * H, msg_b2 + l * H,
                                        upd_w1 + l * 2 * H * H, upd_b1 + l * H,
                                        upd_w2 + l * H * H, upd_b2 + l * H, x,
                                        wxn, b1n, an_);
    }
    k_pool<<<NMOL, 256, 0, stream>>>(x, batch, out_w1, out_b1, out_w2, out_b2, out);
}